// Round 10
// baseline (78.855 us; speedup 1.0000x reference)
//
#include <hip/hip_runtime.h>

// Cost volume: out[b,d,h,w] = (1/C) * sum_c L[c,w] * R[c,w-d], zero for w<d.
// B=8, C=128, H=96, W=320, D=48, fp32 in/out.
//
// Round 10: MFMA rewrite. G[w,w'] = sum_c L[c,w]R[c,w'] is a banded Gram matrix;
// band d=w-w' in [0,48). v_mfma_f32_16x16x32_f16:
//   A-frag = L^T tile: m=w (lane&15), k=c (8 per lane, (lane>>4)*8+j)
//   B-frag = R tile:   n=w' (lane&15), k=c  (same k mapping -> any k-permutation
//            cancels between A and B, so only the VERIFIED C/D layout matters:
//            col = lane&15 = w', row = (lane>>4)*4+reg = w  [learn_hip m89])
// Per 16-w tile: 4 B-tiles at w' offsets {-48,-32,-16,0} cover the band (48/64 kept).
// Wave owns 64 w's (4 w-tiles) -> sliding 7-frag B window shared in-register.
// NO LDS, NO BARRIERS (r8's lesson: barrier vmcnt-drain was the big stall).
// Fragments load direct from global: each load = 4x64B fully-used segments;
// L read once, R ~1.75x (window overlap) -> L2/L3 absorbs (inputs ~L3-resident).
// Boundary: clamp load offset >= 0 (garbage), select 0 at store when w' < 0 (== w<d).
// r9 lesson: keep (b,h)-correlated waves together + bijective XCD swizzle (960%8==0).

typedef _Float16 half8 __attribute__((ext_vector_type(8)));
typedef float f32x4 __attribute__((ext_vector_type(4)));

constexpr int Cn = 128, Hn = 96, Wn = 320, Dn = 48;
constexpr long long PL = (long long)Hn * Wn;   // 30720

__device__ __forceinline__ half8 load_frag(const float* __restrict__ P, long long o) {
  half8 f;
#pragma unroll
  for (int j = 0; j < 8; ++j) f[j] = (_Float16)P[o + (long long)j * PL];
  return f;
}

__global__ __launch_bounds__(256)
void costvol_kernel(const float* __restrict__ L, const float* __restrict__ R,
                    float* __restrict__ out) {
  const int bid = blockIdx.x;
  const int swz = (bid & 7) * 120 + (bid >> 3);   // XCD-contiguous work (bijective)
  const int wid = threadIdx.x >> 6, lane = threadIdx.x & 63;
  const int gw = swz * 4 + wid;                   // 3840 = 768 (b,h) x 5 w-slots
  const int bh = gw / 5, ws = gw - bh * 5;
  const int b = bh / Hn, h = bh - b * Hn;
  const int wbase = ws * 64;
  const int lo = lane & 15, hi = lane >> 4;

  const long long base = (long long)b * Cn * PL + (long long)h * Wn;

  f32x4 acc[4][4];   // [w-tile][b-tile], statically indexed everywhere
#pragma unroll
  for (int i = 0; i < 4; ++i)
#pragma unroll
    for (int j = 0; j < 4; ++j)
      acc[i][j] = f32x4{0.f, 0.f, 0.f, 0.f};

  for (int kc = 0; kc < 4; ++kc) {
    const long long cb = base + (long long)(kc * 32 + hi * 8) * PL;

    // B window: frag i holds R[c][wbase + 16*i - 48 + lo]; w-tile wt uses i = wt..wt+3
    // (delta = w - w' base = 48 - 16*bt). Named scalars -> static liveness, no arrays.
    long long o;
    o = cb + (wbase - 48 + lo); o = o < 0 ? 0 : o;  half8 bw0 = load_frag(R, o);
    o = cb + (wbase - 32 + lo); o = o < 0 ? 0 : o;  half8 bw1 = load_frag(R, o);
    o = cb + (wbase - 16 + lo); o = o < 0 ? 0 : o;  half8 bw2 = load_frag(R, o);

    // wt = 0
    half8 bw3 = load_frag(R, cb + (wbase + 0 + lo));
    {
      const half8 a = load_frag(L, cb + (wbase + 0 + lo));
      acc[0][0] = __builtin_amdgcn_mfma_f32_16x16x32_f16(a, bw0, acc[0][0], 0, 0, 0);
      acc[0][1] = __builtin_amdgcn_mfma_f32_16x16x32_f16(a, bw1, acc[0][1], 0, 0, 0);
      acc[0][2] = __builtin_amdgcn_mfma_f32_16x16x32_f16(a, bw2, acc[0][2], 0, 0, 0);
      acc[0][3] = __builtin_amdgcn_mfma_f32_16x16x32_f16(a, bw3, acc[0][3], 0, 0, 0);
    }
    // wt = 1
    half8 bw4 = load_frag(R, cb + (wbase + 16 + lo));
    {
      const half8 a = load_frag(L, cb + (wbase + 16 + lo));
      acc[1][0] = __builtin_amdgcn_mfma_f32_16x16x32_f16(a, bw1, acc[1][0], 0, 0, 0);
      acc[1][1] = __builtin_amdgcn_mfma_f32_16x16x32_f16(a, bw2, acc[1][1], 0, 0, 0);
      acc[1][2] = __builtin_amdgcn_mfma_f32_16x16x32_f16(a, bw3, acc[1][2], 0, 0, 0);
      acc[1][3] = __builtin_amdgcn_mfma_f32_16x16x32_f16(a, bw4, acc[1][3], 0, 0, 0);
    }
    // wt = 2
    half8 bw5 = load_frag(R, cb + (wbase + 32 + lo));
    {
      const half8 a = load_frag(L, cb + (wbase + 32 + lo));
      acc[2][0] = __builtin_amdgcn_mfma_f32_16x16x32_f16(a, bw2, acc[2][0], 0, 0, 0);
      acc[2][1] = __builtin_amdgcn_mfma_f32_16x16x32_f16(a, bw3, acc[2][1], 0, 0, 0);
      acc[2][2] = __builtin_amdgcn_mfma_f32_16x16x32_f16(a, bw4, acc[2][2], 0, 0, 0);
      acc[2][3] = __builtin_amdgcn_mfma_f32_16x16x32_f16(a, bw5, acc[2][3], 0, 0, 0);
    }
    // wt = 3
    half8 bw6 = load_frag(R, cb + (wbase + 48 + lo));
    {
      const half8 a = load_frag(L, cb + (wbase + 48 + lo));
      acc[3][0] = __builtin_amdgcn_mfma_f32_16x16x32_f16(a, bw3, acc[3][0], 0, 0, 0);
      acc[3][1] = __builtin_amdgcn_mfma_f32_16x16x32_f16(a, bw4, acc[3][1], 0, 0, 0);
      acc[3][2] = __builtin_amdgcn_mfma_f32_16x16x32_f16(a, bw5, acc[3][2], 0, 0, 0);
      acc[3][3] = __builtin_amdgcn_mfma_f32_16x16x32_f16(a, bw6, acc[3][3], 0, 0, 0);
    }
  }

  // Store: lane holds D[m][n] with m=w (row = hi*4+r), n=w' (col = lo). d = w - w'.
  const float s = 1.f / 128.f;
#pragma unroll
  for (int wt = 0; wt < 4; ++wt)
#pragma unroll
    for (int bt = 0; bt < 4; ++bt)
#pragma unroll
      for (int r = 0; r < 4; ++r) {
        const int w  = wbase + 16 * wt + hi * 4 + r;
        const int wp = wbase + 16 * (wt + bt) - 48 + lo;
        const int d  = w - wp;
        if (d >= 0 && d < Dn) {
          const float v = (wp >= 0) ? acc[wt][bt][r] * s : 0.f;
          out[((long long)b * Dn + d) * PL + (long long)h * Wn + w] = v;
        }
      }
}

extern "C" void kernel_launch(void* const* d_in, const int* in_sizes, int n_in,
                              void* d_out, int out_size, void* d_ws, size_t ws_size,
                              hipStream_t stream) {
  const float* Lf = (const float*)d_in[0];
  const float* Rf = (const float*)d_in[1];
  float* outp = (float*)d_out;
  costvol_kernel<<<dim3(960), dim3(256), 0, stream>>>(Lf, Rf, outp);
}